// Round 3
// baseline (301.848 us; speedup 1.0000x reference)
//
#include <hip/hip_runtime.h>
#include <hip/hip_bf16.h>

#define NV_N 32
#define NV_C 128
#define NV_K 64
#define NV_S 12544
#define ST 64          // s-columns per tile
#define TILES 14       // tiles per block
#define SCHUNK 14      // blocks per image
#define XC 72          // x_c[c][s] stride (bf16 elems): 144 B rows, 16B-aligned (b128 reads)
#define XS2 132        // x_s[s][c] stride (bf16 elems): 264 B rows, 8B-aligned (b64 reads, conflict-free)
#define AS 72          // a_lds[k][s] stride

typedef short short8 __attribute__((ext_vector_type(8)));
typedef short short4v __attribute__((ext_vector_type(4)));
typedef float floatx4 __attribute__((ext_vector_type(4)));

static __device__ __forceinline__ unsigned short f2bf(float f) {
  union { float f; unsigned u; } v; v.f = f;
  unsigned r = v.u + 0x7FFFu + ((v.u >> 16) & 1u);  // RNE
  return (unsigned short)(r >> 16);
}
static __device__ __forceinline__ unsigned pk2(float a, float b) {
  union { __hip_bfloat162 h; unsigned u; } v;
  v.h = __float22bfloat162_rn(make_float2(a, b));   // v_cvt_pk_bf16_f32
  return v.u;
}
static __device__ __forceinline__ short8 pack8(float4 a, float4 b) {
  union { unsigned u[4]; short8 s; } r;
  r.u[0] = pk2(a.x, a.y); r.u[1] = pk2(a.z, a.w);
  r.u[2] = pk2(b.x, b.y); r.u[3] = pk2(b.z, b.w);
  return r.s;
}

__global__ __launch_bounds__(256, 2) void netvlad_main(
    const float* __restrict__ x, const float* __restrict__ conv_w,
    float* __restrict__ vlad_ws, float* __restrict__ asum_ws) {
  __shared__ __attribute__((aligned(16))) unsigned short x_c[NV_C * XC];   // 18432 B
  __shared__ __attribute__((aligned(16))) unsigned short x_s[ST * XS2];    // 16896 B
  __shared__ __attribute__((aligned(16))) unsigned short a_lds[NV_K * AS]; //  9216 B
  __shared__ float asum_sh[4][NV_K];                                       //  1024 B

  const int t = threadIdx.x;
  const int n = blockIdx.x / SCHUNK;
  const int chunk = blockIdx.x % SCHUNK;
  const int s_base = chunk * (ST * TILES);
  const int w = t >> 6;        // wave 0..3
  const int lane = t & 63;
  const int q = lane >> 4;     // quad 0..3
  const int l = lane & 15;

  const float* __restrict__ xn = x + (size_t)n * NV_C * NV_S;

  // ---- preload W as A-operand fragments: lane holds W[mt*16+l][kc*32+q*8+j] ----
  short8 wfrag[4][4];
#pragma unroll
  for (int mt = 0; mt < 4; ++mt)
#pragma unroll
    for (int kc = 0; kc < 4; ++kc) {
      const float* wp = conv_w + (mt * 16 + l) * NV_C + kc * 32 + q * 8;
      wfrag[mt][kc] = pack8(*(const float4*)wp, *(const float4*)(wp + 4));
    }

  floatx4 acc2[4][2];   // vlad acc: k=mt*16+q*4+r, c=(w*2+nt)*16+l
  float asum_acc[4][4];
#pragma unroll
  for (int mt = 0; mt < 4; ++mt) {
#pragma unroll
    for (int nt = 0; nt < 2; ++nt) acc2[mt][nt] = (floatx4){0.f, 0.f, 0.f, 0.f};
#pragma unroll
    for (int r = 0; r < 4; ++r) asum_acc[mt][r] = 0.f;
  }

  float4 pf[8];  // prefetch regs: 4 groups x (1 c-row x 8 s)
#pragma unroll
  for (int g = 0; g < 4; ++g) {
    int vec2 = t + g * 256; int c = vec2 >> 3; int sv8 = vec2 & 7;
    const float* p = xn + (size_t)c * NV_S + s_base + sv8 * 8;
    pf[2 * g] = *(const float4*)p;
    pf[2 * g + 1] = *(const float4*)(p + 4);
  }

  for (int tt = 0; tt < TILES; ++tt) {
    __syncthreads();  // S_a: prev GEMM2 (x_c, x_s, a_lds readers) done

    // ---- stage tile: bf16 into both layouts ----
#pragma unroll
    for (int g = 0; g < 4; ++g) {
      int vec2 = t + g * 256; int c = vec2 >> 3; int sv8 = vec2 & 7;
      union { short8 s; unsigned short us[8]; } pk;
      pk.s = pack8(pf[2 * g], pf[2 * g + 1]);
      *(short8*)&x_c[c * XC + sv8 * 8] = pk.s;
#pragma unroll
      for (int j = 0; j < 8; ++j)
        x_s[(sv8 * 8 + j) * XS2 + c] = pk.us[j];
    }
    __syncthreads();  // S_b

    // ---- prefetch tile tt+1 (in flight through all compute) ----
    if (tt + 1 < TILES) {
      const int s0n = s_base + (tt + 1) * ST;
#pragma unroll
      for (int g = 0; g < 4; ++g) {
        int vec2 = t + g * 256; int c = vec2 >> 3; int sv8 = vec2 & 7;
        const float* p = xn + (size_t)c * NV_S + s0n + sv8 * 8;
        pf[2 * g] = *(const float4*)p;
        pf[2 * g + 1] = *(const float4*)(p + 4);
      }
    }

    // ---- GEMM1: logits[64k][16s per wave]; B-frags via 2x ds_read_b64 ----
    floatx4 acc1[4];
#pragma unroll
    for (int mt = 0; mt < 4; ++mt) acc1[mt] = (floatx4){0.f, 0.f, 0.f, 0.f};
#pragma unroll
    for (int kc = 0; kc < 4; ++kc) {
      union { short4v h[2]; short8 s8; } bfr;
      const unsigned short* bp = &x_s[(w * 16 + l) * XS2 + kc * 32 + q * 8];
      bfr.h[0] = *(const short4v*)bp;
      bfr.h[1] = *(const short4v*)(bp + 4);
#pragma unroll
      for (int mt = 0; mt < 4; ++mt)
        acc1[mt] = __builtin_amdgcn_mfma_f32_16x16x32_bf16(wfrag[mt][kc], bfr.s8, acc1[mt], 0, 0, 0);
    }

    // ---- softmax over k=64 per column (no max-sub: |logit| <~ 4, exp safe;
    //      softmax is shift-invariant so result matches reference) ----
    {
      float sum = 0.f;
#pragma unroll
      for (int mt = 0; mt < 4; ++mt)
#pragma unroll
        for (int r = 0; r < 4; ++r) {
          float e = __expf(acc1[mt][r]);
          acc1[mt][r] = e; sum += e;
        }
      sum += __shfl_xor(sum, 16);
      sum += __shfl_xor(sum, 32);
      const float inv = 1.0f / sum;
#pragma unroll
      for (int mt = 0; mt < 4; ++mt)
#pragma unroll
        for (int r = 0; r < 4; ++r) {
          float a = acc1[mt][r] * inv;
          asum_acc[mt][r] += a;
          a_lds[(mt * 16 + q * 4 + r) * AS + w * 16 + l] = f2bf(a);
        }
    }
    __syncthreads();  // S_c: a_lds complete

    // ---- GEMM2: vlad[64k][128c] += a(64x64) * x^T ----
#pragma unroll
    for (int sk = 0; sk < 2; ++sk) {
      short8 afr[4];
#pragma unroll
      for (int mt = 0; mt < 4; ++mt)
        afr[mt] = *(const short8*)&a_lds[(mt * 16 + l) * AS + sk * 32 + q * 8];
#pragma unroll
      for (int nt = 0; nt < 2; ++nt) {
        const short8 bfr = *(const short8*)&x_c[((w * 2 + nt) * 16 + l) * XC + sk * 32 + q * 8];
#pragma unroll
        for (int mt = 0; mt < 4; ++mt)
          acc2[mt][nt] = __builtin_amdgcn_mfma_f32_16x16x32_bf16(afr[mt], bfr, acc2[mt][nt], 0, 0, 0);
      }
    }
  }

  // ---- epilogue: per-chunk partials, NO atomics ----
#pragma unroll
  for (int mt = 0; mt < 4; ++mt)
#pragma unroll
    for (int r = 0; r < 4; ++r) {
      float v = asum_acc[mt][r];
      v += __shfl_xor(v, 1); v += __shfl_xor(v, 2);
      v += __shfl_xor(v, 4); v += __shfl_xor(v, 8);
      if (l == 0) asum_sh[w][mt * 16 + q * 4 + r] = v;
    }
  __syncthreads();
  const size_t slab = (size_t)(n * SCHUNK + chunk);
  if (t < NV_K)
    asum_ws[slab * NV_K + t] =
        asum_sh[0][t] + asum_sh[1][t] + asum_sh[2][t] + asum_sh[3][t];

  float* vw = vlad_ws + slab * (NV_K * NV_C);
#pragma unroll
  for (int mt = 0; mt < 4; ++mt)
#pragma unroll
    for (int nt = 0; nt < 2; ++nt)
#pragma unroll
      for (int r = 0; r < 4; ++r)
        vw[(mt * 16 + q * 4 + r) * NV_C + (w * 2 + nt) * 16 + l] = acc2[mt][nt][r];
}

// 256 blocks: (n, k-octet). Sum 14 chunk partials, subtract asum*centroid.
__global__ __launch_bounds__(256) void netvlad_reduce(
    const float* __restrict__ vlad_ws, const float* __restrict__ asum_ws,
    const float* __restrict__ cent, float* __restrict__ vlad_f) {
  const int t = threadIdx.x;
  const int n = blockIdx.x >> 3;
  const int k = (blockIdx.x & 7) * 8 + (t >> 5);
  const int c4 = (t & 31) * 4;

  float as = 0.f;
  float4 acc = {0.f, 0.f, 0.f, 0.f};
#pragma unroll
  for (int ch = 0; ch < SCHUNK; ++ch) {
    const size_t slab = (size_t)(n * SCHUNK + ch);
    as += asum_ws[slab * NV_K + k];
    float4 p = *(const float4*)&vlad_ws[slab * (NV_K * NV_C) + k * NV_C + c4];
    acc.x += p.x; acc.y += p.y; acc.z += p.z; acc.w += p.w;
  }
  float4 ce = *(const float4*)&cent[k * NV_C + c4];
  float4 v;
  v.x = acc.x - as * ce.x; v.y = acc.y - as * ce.y;
  v.z = acc.z - as * ce.z; v.w = acc.w - as * ce.w;
  *(float4*)&vlad_f[(size_t)n * (NV_K * NV_C) + k * NV_C + c4] = v;
}

__global__ __launch_bounds__(256) void netvlad_finalize(
    const float* __restrict__ vlad_f, float* __restrict__ out) {
  __shared__ float v_lds[NV_K * NV_C];  // 32 KB
  __shared__ float red4[256];
  __shared__ float rscale[NV_K];
  __shared__ float gscale_sh;

  const int t = threadIdx.x; const int n = blockIdx.x;
  const float* vf = vlad_f + (size_t)n * (NV_K * NV_C);

#pragma unroll
  for (int i = 0; i < 8; ++i) {
    int vec = t + i * 256; int k = vec >> 5; int cq = vec & 31;
    *(float4*)&v_lds[k * NV_C + cq * 4] = *(const float4*)(vf + k * NV_C + cq * 4);
  }
  __syncthreads();

  {  // per-cluster sumsq
    const int k = t >> 2, part = t & 3;
    const float* row = &v_lds[k * NV_C + part * 32];
    float ss = 0.0f;
#pragma unroll
    for (int c = 0; c < 32; ++c) { float v = row[c]; ss += v * v; }
    red4[t] = ss;
  }
  __syncthreads();
  if (t < NV_K) {
    float ss = red4[t * 4] + red4[t * 4 + 1] + red4[t * 4 + 2] + red4[t * 4 + 3];
    rscale[t] = 1.0f / fmaxf(sqrtf(ss), 1e-12f);
  }
  __syncthreads();

  float gp = 0.0f;
#pragma unroll
  for (int i = 0; i < 8; ++i) {
    int vec = t + i * 256; int k = vec >> 5; int cq = vec & 31;
    float4 v = *(const float4*)&v_lds[k * NV_C + cq * 4];
    float rs = rscale[k];
    gp += (v.x * v.x + v.y * v.y + v.z * v.z + v.w * v.w) * rs * rs;
  }
  red4[t] = gp;
  __syncthreads();
  if (t < 64) {
    float s = red4[t] + red4[t + 64] + red4[t + 128] + red4[t + 192];
#pragma unroll
    for (int o = 32; o > 0; o >>= 1) s += __shfl_down(s, o);
    if (t == 0) gscale_sh = 1.0f / fmaxf(sqrtf(s), 1e-12f);
  }
  __syncthreads();
  const float gs = gscale_sh;

#pragma unroll
  for (int i = 0; i < 8; ++i) {
    int vec = t + i * 256; int k = vec >> 5; int cq = vec & 31;
    float4 v = *(const float4*)&v_lds[k * NV_C + cq * 4];
    const float sc = rscale[k] * gs;
    v.x *= sc; v.y *= sc; v.z *= sc; v.w *= sc;
    *(float4*)(out + (size_t)n * (NV_K * NV_C) + k * NV_C + cq * 4) = v;
  }
}

extern "C" void kernel_launch(void* const* d_in, const int* in_sizes, int n_in,
                              void* d_out, int out_size, void* d_ws, size_t ws_size,
                              hipStream_t stream) {
  (void)in_sizes; (void)n_in; (void)out_size; (void)ws_size;
  const float* x      = (const float*)d_in[0];
  const float* conv_w = (const float*)d_in[1];
  const float* cent   = (const float*)d_in[2];
  float* out = (float*)d_out;

  float* vlad_ws = (float*)d_ws;                                    // 32*14*8192
  float* asum_ws = vlad_ws + (size_t)NV_N * SCHUNK * NV_K * NV_C;   // 32*14*64
  float* vlad_f  = asum_ws + (size_t)NV_N * SCHUNK * NV_K;          // 32*8192

  hipLaunchKernelGGL(netvlad_main, dim3(NV_N * SCHUNK), dim3(256), 0, stream,
                     x, conv_w, vlad_ws, asum_ws);
  hipLaunchKernelGGL(netvlad_reduce, dim3(NV_N * 8), dim3(256), 0, stream,
                     vlad_ws, asum_ws, cent, vlad_f);
  hipLaunchKernelGGL(netvlad_finalize, dim3(NV_N), dim3(256), 0, stream,
                     vlad_f, out);
}